// Round 1
// baseline (450.068 us; speedup 1.0000x reference)
//
#include <hip/hip_runtime.h>

// Blur_1803886264378: depthwise 4x4 upfirdn2d blur, fp32.
// B=8, C=128, H=W=256, pad=(2,1) both dims -> same-size output.
// out[i,j] = sum_{di,dj} w[di][dj] * x[i+di-2][j+dj-2]  (zero outside)
// where w = flip(kernel). Kernel is rank-1; factor w[di][dj] = u[di]*v[dj]
// at runtime (exact in fp32 for the [1,3,3,1] kernel) and do the separable
// blur fused in one kernel with a rolling 4-row window of horizontal results.

#define BB 8
#define CC 128
#define HH 256
#define WW 256

// lane (0..63) = float4 column window -> 64 lanes cover full row, coalesced.
// wave (0..3 per block) owns an 8-row strip; block covers 32 contiguous rows.
// grid = B*C*8 blocks.
__global__ __launch_bounds__(256) void blur_kernel(
    const float* __restrict__ x, const float* __restrict__ kern,
    float* __restrict__ out)
{
    const int lane  = threadIdx.x & 63;
    const int wv    = threadIdx.x >> 6;
    const int strip = blockIdx.x & 7;
    const int bc    = blockIdx.x >> 3;

    const int row0 = strip * 32 + wv * 8;   // first output row for this wave
    const int col0 = lane * 4;              // first output col for this lane

    // Flipped kernel: w[di][dj] = kern[(3-di)*4 + (3-dj)].
    // Rank-1 factorization: v[dj] = w[0][dj], u[di] = w[di][0]/w[0][0] (u0==1).
    const float w00 = kern[15];
    const float v0 = kern[15], v1 = kern[14], v2 = kern[13], v3 = kern[12];
    const float u1 = kern[11] / w00;   // w[1][0] = kern[2*4+3]
    const float u2 = kern[7]  / w00;   // w[2][0] = kern[1*4+3]
    const float u3 = kern[3]  / w00;   // w[3][0] = kern[0*4+3]

    const float* base  = x   + (size_t)bc * (HH * WW);
    float*       obase = out + (size_t)bc * (HH * WW);

    const bool has_left  = (lane != 0);    // cols col0-2, col0-1 exist
    const bool has_right = (lane != 63);   // col col0+4 exists

    // Horizontal 4-tap blur of input row r over this lane's 4 output cols.
    auto hrow = [&](int r) -> float4 {
        float4 h = make_float4(0.f, 0.f, 0.f, 0.f);
        if (r < 0 || r >= HH) return h;          // wave-uniform branch
        const float* rp = base + r * WW + col0;
        const float4 mid = *(const float4*)rp;   // cols col0..col0+3 (16B aligned)
        float xm2 = 0.f, xm1 = 0.f, x4 = 0.f;
        if (has_left) {                          // 8B-aligned float2
            const float2 l = *(const float2*)(rp - 2);
            xm2 = l.x; xm1 = l.y;
        }
        if (has_right) x4 = rp[4];
        h.x = v0*xm2   + v1*xm1   + v2*mid.x + v3*mid.y;
        h.y = v0*xm1   + v1*mid.x + v2*mid.y + v3*mid.z;
        h.z = v0*mid.x + v1*mid.y + v2*mid.z + v3*mid.w;
        h.w = v0*mid.y + v1*mid.z + v2*mid.w + v3*x4;
        return h;
    };

    // Rolling window: out[r] = u0*H[r-2] + u1*H[r-1] + u2*H[r] + u3*H[r+1]
    float4 h0 = hrow(row0 - 2);
    float4 h1 = hrow(row0 - 1);
    float4 h2 = hrow(row0);
    #pragma unroll
    for (int k = 0; k < 8; ++k) {
        const float4 h3 = hrow(row0 + 1 + k);
        float4 o;
        o.x = h0.x + u1*h1.x + u2*h2.x + u3*h3.x;   // u0 == 1 by construction
        o.y = h0.y + u1*h1.y + u2*h2.y + u3*h3.y;
        o.z = h0.z + u1*h1.z + u2*h2.z + u3*h3.z;
        o.w = h0.w + u1*h1.w + u2*h2.w + u3*h3.w;
        *(float4*)(obase + (row0 + k) * WW + col0) = o;
        h0 = h1; h1 = h2; h2 = h3;
    }
}

extern "C" void kernel_launch(void* const* d_in, const int* in_sizes, int n_in,
                              void* d_out, int out_size, void* d_ws, size_t ws_size,
                              hipStream_t stream) {
    const float* x    = (const float*)d_in[0];
    const float* kern = (const float*)d_in[1];
    float*       out  = (float*)d_out;
    const dim3 grid(BB * CC * 8);   // 8192 blocks
    const dim3 block(256);
    blur_kernel<<<grid, block, 0, stream>>>(x, kern, out);
}

// Round 2
// 443.117 us; speedup vs baseline: 1.0157x; 1.0157x over previous
//
#include <hip/hip_runtime.h>

// Blur_1803886264378: depthwise 4x4 upfirdn2d blur, fp32.
// B=8, C=128, H=W=256, pad=(2,1) both dims -> same-size output.
// Separable (rank-1 [1,3,3,1] x [1,3,3,1]) blur fused in one kernel.
//
// R2 changes vs R1:
//  - Horizontal halo via cross-lane shuffles instead of extra global loads
//    (1 VMEM instr/row instead of 3; W=256 = exactly one wave of float4,
//    so wave edges == image edges == zeros).
//  - 16-row strips per wave (was 8): halo re-blur 19/16 vs 11/8, fewer
//    threads, amortized addressing.

#define BB 8
#define CC 128
#define HH 256
#define WW 256
#define RPW 16   // rows per wave

__global__ __launch_bounds__(256) void blur_kernel(
    const float* __restrict__ x, const float* __restrict__ kern,
    float* __restrict__ out)
{
    const int lane  = threadIdx.x & 63;
    const int wv    = threadIdx.x >> 6;
    const int strip = blockIdx.x & 3;       // 4 block-strips of 64 rows
    const int bc    = blockIdx.x >> 2;

    const int row0 = strip * 64 + wv * RPW; // first output row for this wave
    const int col0 = lane * 4;              // first output col for this lane

    // Flipped kernel: w[di][dj] = kern[(3-di)*4 + (3-dj)].
    // Rank-1: v[dj] = w[0][dj], u[di] = w[di][0]/w[0][0] (u0 == 1).
    const float w00 = kern[15];
    const float v0 = kern[15], v1 = kern[14], v2 = kern[13], v3 = kern[12];
    const float u1 = kern[11] / w00;
    const float u2 = kern[7]  / w00;
    const float u3 = kern[3]  / w00;

    const float* base  = x   + (size_t)bc * (HH * WW);
    float*       obase = out + (size_t)bc * (HH * WW);

    const bool l0  = (lane == 0);
    const bool l63 = (lane == 63);

    // Horizontal 4-tap blur of input row r over this lane's 4 output cols.
    // Halo values come from neighbor lanes' registers via shuffle; the wave
    // spans the full row, so lane-0 left / lane-63 right halos are zeros.
    auto hrow = [&](int r) -> float4 {
        float4 h = make_float4(0.f, 0.f, 0.f, 0.f);
        if (r < 0 || r >= HH) return h;          // wave-uniform branch
        const float4 mid = *(const float4*)(base + r * WW + col0);
        float xm2 = __shfl_up(mid.z, 1);         // x[col0-2]
        float xm1 = __shfl_up(mid.w, 1);         // x[col0-1]
        float x4  = __shfl_down(mid.x, 1);       // x[col0+4]
        if (l0)  { xm2 = 0.f; xm1 = 0.f; }
        if (l63) { x4 = 0.f; }
        h.x = v0*xm2   + v1*xm1   + v2*mid.x + v3*mid.y;
        h.y = v0*xm1   + v1*mid.x + v2*mid.y + v3*mid.z;
        h.z = v0*mid.x + v1*mid.y + v2*mid.z + v3*mid.w;
        h.w = v0*mid.y + v1*mid.z + v2*mid.w + v3*x4;
        return h;
    };

    // Rolling window: out[r] = H[r-2] + u1*H[r-1] + u2*H[r] + u3*H[r+1]
    float4 h0 = hrow(row0 - 2);
    float4 h1 = hrow(row0 - 1);
    float4 h2 = hrow(row0);
    #pragma unroll
    for (int k = 0; k < RPW; ++k) {
        const float4 h3 = hrow(row0 + 1 + k);
        float4 o;
        o.x = h0.x + u1*h1.x + u2*h2.x + u3*h3.x;   // u0 == 1
        o.y = h0.y + u1*h1.y + u2*h2.y + u3*h3.y;
        o.z = h0.z + u1*h1.z + u2*h2.z + u3*h3.z;
        o.w = h0.w + u1*h1.w + u2*h2.w + u3*h3.w;
        *(float4*)(obase + (row0 + k) * WW + col0) = o;
        h0 = h1; h1 = h2; h2 = h3;
    }
}

extern "C" void kernel_launch(void* const* d_in, const int* in_sizes, int n_in,
                              void* d_out, int out_size, void* d_ws, size_t ws_size,
                              hipStream_t stream) {
    const float* x    = (const float*)d_in[0];
    const float* kern = (const float*)d_in[1];
    float*       out  = (float*)d_out;
    const dim3 grid(BB * CC * (HH / 64)); // 4096 blocks (4 waves x 16 rows each)
    const dim3 block(256);
    blur_kernel<<<grid, block, 0, stream>>>(x, kern, out);
}